// Round 9
// baseline (148.643 us; speedup 1.0000x reference)
//
#include <hip/hip_runtime.h>

// Problem constants (reference: N=16, A=2048, B=2048, H=64)
#define NB 16
#define AQ 2048
#define BKV 2048
#define HD 64

#define QSCALE 0.18033688f  // 0.125 * log2(e): softmax done in log2 domain
#define MBIAS -43000.0f     // additive mask bias (log2 units); exp2 -> exact 0

typedef float f32x4 __attribute__((ext_vector_type(4)));
typedef float f32x16 __attribute__((ext_vector_type(16)));
typedef short bf16x8 __attribute__((ext_vector_type(8)));
typedef int int4v __attribute__((ext_vector_type(4)));

__device__ __forceinline__ short f2bf(float f) {
  return __builtin_bit_cast(short, static_cast<__bf16>(f));
}
__device__ __forceinline__ unsigned pk2(float a, float b) {
  unsigned lo = (unsigned short)f2bf(a);
  unsigned hh = (unsigned short)f2bf(b);
  return lo | (hh << 16);
}

// -------------------- fused prepass (single launch, round-6 verified) --------
// blocks [0, 1024):   K f32 [n][b][h] -> Kb bf16 [n][b][h]
// blocks [1024, 1536): V f32 [n][b][h] -> Vt bf16 [n][h][b]  (64x64 LDS tile)
__global__ __launch_bounds__(256) void prepack(const float* __restrict__ K,
                                               const float* __restrict__ V,
                                               short* __restrict__ Kb,
                                               short* __restrict__ Vt) {
  if (blockIdx.x < 1024) {
    size_t base = ((size_t)blockIdx.x * 256 + threadIdx.x) * 8;
    f32x4 a = *(const f32x4*)(K + base);
    f32x4 b = *(const f32x4*)(K + base + 4);
    bf16x8 o;
#pragma unroll
    for (int i = 0; i < 4; ++i) {
      o[i] = f2bf(a[i]);
      o[i + 4] = f2bf(b[i]);
    }
    *(bf16x8*)(Kb + base) = o;
  } else {
    unsigned vb = blockIdx.x - 1024;
    int n = vb >> 5;
    int b0 = (vb & 31) * 64;
    int t = threadIdx.x;
    __shared__ short tile[64][68];
    int rb = t >> 4;
    int hc = (t & 15) * 4;
#pragma unroll
    for (int j = 0; j < 4; ++j) {
      int r = rb + 16 * j;
      f32x4 v = *(const f32x4*)(V + ((size_t)n * BKV + b0 + r) * HD + hc);
#pragma unroll
      for (int i = 0; i < 4; ++i) tile[r][hc + i] = f2bf(v[i]);
    }
    __syncthreads();
    int hr = t >> 2;
    int bb = (t & 3) * 16;
    bf16x8 o0, o1;
#pragma unroll
    for (int j = 0; j < 8; ++j) {
      o0[j] = tile[bb + j][hr];
      o1[j] = tile[bb + 8 + j][hr];
    }
    short* dst = Vt + ((size_t)n * HD + hr) * BKV + b0 + bb;
    *(bf16x8*)dst = o0;
    *(bf16x8*)(dst + 8) = o1;
  }
}

// ---------------------------- main flash kernel ------------------------------
// 32x32x16 MFMA, BOTH GEMMs swapped: S^T = mfma(K, Q), O^T = mfma(V^T, P^T).
// C/D col = lane&31 = q for both -> all softmax state lane-local in q:
// no shfl for acc rescale, no LDS for P, 1 shfl_xor(32) per reduce.
// Mask folded into QK^T C-init (additive -43000 bias, log2 domain).
// Block = 4 waves, ALL sharing the same 32 q rows; wave w owns KV quarter
// [w*512,(w+1)*512); 4-way merge through LDS at the end.
// Grid = N * A/32 = 1024 blocks = 4 blocks/CU exactly (round-8 post-mortem:
// latency-bound at 21% occupancy; this doubles resident waves to 50%).
// LDS 35.8 KB -> exactly 4 blocks/CU. __launch_bounds__(256, 4): VGPR cap 128.
// DO NOT raise min-waves to 8 — 64-VGPR cap spills acc (rounds 5/7:
// WRITE_SIZE 114-198 MB; keep WRITE_SIZE ~8 MB as the spill tripwire).
template <int PRE>
__global__ __launch_bounds__(256, 4) void attn_fwd(
    const float* __restrict__ Q, const float* __restrict__ K,
    const float* __restrict__ V, const int* __restrict__ M,
    const short* __restrict__ Kb, const short* __restrict__ Vt,
    float* __restrict__ O) {
  // bijective XCD swizzle: 1024 blocks, 128 contiguous wgs per XCD (2 batches)
  unsigned orig = blockIdx.x;
  unsigned wg = (orig & 7u) * 128u + (orig >> 3);
  int n = (int)(wg >> 6);          // 64 q-tiles per batch
  int q0 = (int)(wg & 63u) * 32;   // block's 32 q rows

  int w = threadIdx.x >> 6;  // wave 0..3 -> KV quarter
  int lane = threadIdx.x & 63;
  int hi = lane >> 5;        // half-wave id
  int li = lane & 31;

  const float* Qn = Q + (size_t)n * AQ * HD;
  const float* Kn = K + (size_t)n * BKV * HD;
  const float* Vn = V + (size_t)n * BKV * HD;
  const short* Kbn = Kb + (size_t)n * BKV * HD;
  const short* Vtn = Vt + (size_t)n * HD * BKV;
  const int* Mn = M + (size_t)n * BKV;

  __shared__ __align__(16) float pacc[4][32][68];  // 34816 B partial O^T
  __shared__ float Ml[4][2][32];                   // m, l per wave per q

  // ---- Q fragments (B operand of swapped QK^T), log2-scale folded in.
  // B[k=h][j=q]: lane holds q = q0 + li, h = 16*ks + 8*hi + j (contiguous f32)
  bf16x8 qb[4];
#pragma unroll
  for (int ks = 0; ks < 4; ++ks) {
    const float* qp = Qn + (size_t)(q0 + li) * HD + 16 * ks + 8 * hi;
    f32x4 a = *(const f32x4*)qp;
    f32x4 b = *(const f32x4*)(qp + 4);
#pragma unroll
    for (int i = 0; i < 4; ++i) {
      qb[ks][i] = f2bf(a[i] * QSCALE);
      qb[ks][i + 4] = f2bf(b[i] * QSCALE);
    }
  }

  // acc0/acc1: O^T[h = 32*ht + crow(reg,hi)][q = li], crow = (r&3)+8*(r>>2)+4*hi
  f32x16 acc0 = {};
  f32x16 acc1 = {};
  float m_run = -1e30f;
  float l_run = 0.f;

  const int bstart = w * (BKV / 4);
  for (int b0 = bstart; b0 < bstart + (BKV / 4); b0 += 32) {
    // ---- mask -> C-init bias (row b_loc = 8j + 4hi + r)
    int4v mv[4];
#pragma unroll
    for (int j = 0; j < 4; ++j)
      mv[j] = *(const int4v*)(Mn + b0 + 8 * j + 4 * hi);
    f32x16 st;
#pragma unroll
    for (int j = 0; j < 4; ++j)
#pragma unroll
      for (int r = 0; r < 4; ++r) st[4 * j + r] = mv[j][r] ? MBIAS : 0.f;

    // ---- S^T = K.Q^T (+bias): st[reg] = S^T[b0 + crow(reg,hi)][q0 + li]
#pragma unroll
    for (int ks = 0; ks < 4; ++ks) {
      bf16x8 ka;
      if constexpr (PRE) {
        ka = *(const bf16x8*)(Kbn + (size_t)(b0 + li) * HD + 16 * ks + 8 * hi);
      } else {
        const float* kp = Kn + (size_t)(b0 + li) * HD + 16 * ks + 8 * hi;
        f32x4 k0 = *(const f32x4*)kp;
        f32x4 k1 = *(const f32x4*)(kp + 4);
#pragma unroll
        for (int i = 0; i < 4; ++i) {
          ka[i] = f2bf(k0[i]);
          ka[i + 4] = f2bf(k1[i]);
        }
      }
      st = __builtin_amdgcn_mfma_f32_32x32x16_bf16(ka, qb[ks], st, 0, 0, 0);
    }

    // ---- row max over 32 b (16 own regs + partner half via one shfl)
    float mt = st[0];
#pragma unroll
    for (int i = 1; i < 16; ++i) mt = fmaxf(mt, st[i]);
    mt = fmaxf(mt, __shfl_xor(mt, 32));
    float m_new = fmaxf(m_run, mt);
    float fac = exp2f(m_run - m_new);

    // ---- P = exp2(S - m) in place (log2 domain; masked -> exactly 0)
    float rs = 0.f;
#pragma unroll
    for (int i = 0; i < 16; ++i) {
      float e = exp2f(st[i] - m_new);
      st[i] = e;
      rs += e;
    }
    rs += __shfl_xor(rs, 32);
    l_run = l_run * fac + rs;
    m_run = m_new;

    // ---- rescale acc (fac is lane-local in q — no shfl!)
#pragma unroll
    for (int i = 0; i < 16; ++i) {
      acc0[i] *= fac;
      acc1[i] *= fac;
    }

    // ---- P^T B-operand: pack to bf16 words, redistribute across half-waves.
    // own words w8[j] = P[q][b-pair]; partner's via shfl_xor(32); select by hi.
    unsigned w8[8], sx[8];
#pragma unroll
    for (int j = 0; j < 8; ++j) w8[j] = pk2(st[2 * j], st[2 * j + 1]);
#pragma unroll
    for (int j = 0; j < 8; ++j) sx[j] = (unsigned)__shfl_xor((int)w8[j], 32);
    int4v p0 = {(int)(hi ? sx[2] : w8[0]), (int)(hi ? sx[3] : w8[1]),
                (int)(hi ? w8[2] : sx[0]), (int)(hi ? w8[3] : sx[1])};
    int4v p1 = {(int)(hi ? sx[6] : w8[4]), (int)(hi ? sx[7] : w8[5]),
                (int)(hi ? w8[6] : sx[4]), (int)(hi ? w8[7] : sx[5])};
    bf16x8 pb0 = __builtin_bit_cast(bf16x8, p0);
    bf16x8 pb1 = __builtin_bit_cast(bf16x8, p1);

    // ---- O^T += V^T . P^T : A[i=h][k=b] from Vt (contiguous bf16x8)
#pragma unroll
    for (int ht = 0; ht < 2; ++ht) {
      bf16x8 va0, va1;
      if constexpr (PRE) {
        const short* vp = Vtn + (size_t)(32 * ht + li) * BKV + b0 + 8 * hi;
        va0 = *(const bf16x8*)vp;
        va1 = *(const bf16x8*)(vp + 16);
      } else {
#pragma unroll
        for (int j = 0; j < 8; ++j) {
          va0[j] = f2bf(Vn[(size_t)(b0 + 8 * hi + j) * HD + 32 * ht + li]);
          va1[j] = f2bf(Vn[(size_t)(b0 + 16 + 8 * hi + j) * HD + 32 * ht + li]);
        }
      }
      if (ht == 0) {
        acc0 = __builtin_amdgcn_mfma_f32_32x32x16_bf16(va0, pb0, acc0, 0, 0, 0);
        acc0 = __builtin_amdgcn_mfma_f32_32x32x16_bf16(va1, pb1, acc0, 0, 0, 0);
      } else {
        acc1 = __builtin_amdgcn_mfma_f32_32x32x16_bf16(va0, pb0, acc1, 0, 0, 0);
        acc1 = __builtin_amdgcn_mfma_f32_32x32x16_bf16(va1, pb1, acc1, 0, 0, 0);
      }
    }
  }

  // ---- publish per-wave partials (m, l lane-local; acc^T scattered to [q][h])
  if (hi == 0) {
    Ml[w][0][li] = m_run;
    Ml[w][1][li] = l_run;
  }
#pragma unroll
  for (int reg = 0; reg < 16; ++reg) {
    int hrow = (reg & 3) + 8 * (reg >> 2) + 4 * hi;
    pacc[w][li][hrow] = acc0[reg];
    pacc[w][li][32 + hrow] = acc1[reg];
  }
  __syncthreads();

  // ---- merge 4 KV-quarter partials; 256 threads cover 32 q x 8 h-octets
  {
    int tid = threadIdx.x;
    int q = tid >> 3;          // 0..31
    int hb = (tid & 7) * 8;    // 0,8,...,56
    float m0 = Ml[0][0][q], m1 = Ml[1][0][q];
    float m2 = Ml[2][0][q], m3 = Ml[3][0][q];
    float mmax = fmaxf(fmaxf(m0, m1), fmaxf(m2, m3));
    float f[4] = {exp2f(m0 - mmax), exp2f(m1 - mmax), exp2f(m2 - mmax),
                  exp2f(m3 - mmax)};
    float l = f[0] * Ml[0][1][q] + f[1] * Ml[1][1][q] + f[2] * Ml[2][1][q] +
              f[3] * Ml[3][1][q];
    float inv = 1.0f / l;
    float* op = O + ((size_t)n * AQ + q0 + q) * HD + hb;
#pragma unroll
    for (int t = 0; t < 2; ++t) {
      f32x4 o = {0.f, 0.f, 0.f, 0.f};
#pragma unroll
      for (int ww = 0; ww < 4; ++ww) {
        f32x4 a = *(const f32x4*)&pacc[ww][q][hb + 4 * t];
#pragma unroll
        for (int i = 0; i < 4; ++i) o[i] += f[ww] * a[i];
      }
      f32x4 res;
#pragma unroll
      for (int i = 0; i < 4; ++i) res[i] = o[i] * inv;
      *(f32x4*)(op + 4 * t) = res;
    }
  }
}

extern "C" void kernel_launch(void* const* d_in, const int* in_sizes, int n_in,
                              void* d_out, int out_size, void* d_ws, size_t ws_size,
                              hipStream_t stream) {
  const float* q = (const float*)d_in[0];
  const float* k = (const float*)d_in[1];
  const float* v = (const float*)d_in[2];
  const int* m = (const int*)d_in[3];
  float* o = (float*)d_out;

  const size_t kv_elems = (size_t)NB * BKV * HD;     // 2,097,152
  const size_t need = kv_elems * 2 * sizeof(short);  // Kb + Vt = 8 MB

  if (ws_size >= need) {
    short* kb = (short*)d_ws;
    short* vt = kb + kv_elems;
    prepack<<<dim3(1536), dim3(256), 0, stream>>>(k, v, kb, vt);
    attn_fwd<1><<<dim3(NB * (AQ / 32)), dim3(256), 0, stream>>>(q, k, v, m, kb, vt, o);
  } else {
    attn_fwd<0><<<dim3(NB * (AQ / 32)), dim3(256), 0, stream>>>(q, k, v, m, nullptr, nullptr, o);
  }
}

// Round 12
// 147.560 us; speedup vs baseline: 1.0073x; 1.0073x over previous
//
#include <hip/hip_runtime.h>

// Problem constants (reference: N=16, A=2048, B=2048, H=64)
#define NB 16
#define AQ 2048
#define BKV 2048
#define HD 64

#define QSCALE 0.18033688f  // 0.125 * log2(e): softmax done in log2 domain
#define MBIAS -43000.0f     // additive mask bias (log2 units); exp2 -> exact 0
#define DTHR 8.0f           // defer-max threshold (log2 units): P <= 2^8

typedef float f32x4 __attribute__((ext_vector_type(4)));
typedef float f32x16 __attribute__((ext_vector_type(16)));
typedef short bf16x8 __attribute__((ext_vector_type(8)));
typedef int int4v __attribute__((ext_vector_type(4)));

__device__ __forceinline__ short f2bf(float f) {
  return __builtin_bit_cast(short, static_cast<__bf16>(f));
}
__device__ __forceinline__ unsigned pk2(float a, float b) {
  unsigned lo = (unsigned short)f2bf(a);
  unsigned hh = (unsigned short)f2bf(b);
  return lo | (hh << 16);
}

// -------------------- fused prepass (single launch, round-6 verified) --------
// blocks [0, 1024):   K f32 [n][b][h] -> Kb bf16 [n][b][h]
// blocks [1024, 1536): V f32 [n][b][h] -> Vt bf16 [n][h][b]  (64x64 LDS tile)
__global__ __launch_bounds__(256) void prepack(const float* __restrict__ K,
                                               const float* __restrict__ V,
                                               short* __restrict__ Kb,
                                               short* __restrict__ Vt) {
  if (blockIdx.x < 1024) {
    size_t base = ((size_t)blockIdx.x * 256 + threadIdx.x) * 8;
    f32x4 a = *(const f32x4*)(K + base);
    f32x4 b = *(const f32x4*)(K + base + 4);
    bf16x8 o;
#pragma unroll
    for (int i = 0; i < 4; ++i) {
      o[i] = f2bf(a[i]);
      o[i + 4] = f2bf(b[i]);
    }
    *(bf16x8*)(Kb + base) = o;
  } else {
    unsigned vb = blockIdx.x - 1024;
    int n = vb >> 5;
    int b0 = (vb & 31) * 64;
    int t = threadIdx.x;
    __shared__ short tile[64][68];
    int rb = t >> 4;
    int hc = (t & 15) * 4;
#pragma unroll
    for (int j = 0; j < 4; ++j) {
      int r = rb + 16 * j;
      f32x4 v = *(const f32x4*)(V + ((size_t)n * BKV + b0 + r) * HD + hc);
#pragma unroll
      for (int i = 0; i < 4; ++i) tile[r][hc + i] = f2bf(v[i]);
    }
    __syncthreads();
    int hr = t >> 2;
    int bb = (t & 3) * 16;
    bf16x8 o0, o1;
#pragma unroll
    for (int j = 0; j < 8; ++j) {
      o0[j] = tile[bb + j][hr];
      o1[j] = tile[bb + 8 + j][hr];
    }
    short* dst = Vt + ((size_t)n * HD + hr) * BKV + b0 + bb;
    *(bf16x8*)dst = o0;
    *(bf16x8*)(dst + 8) = o1;
  }
}

// ---------------------------- main flash kernel ------------------------------
// 32x32x16 MFMA, BOTH GEMMs swapped: S^T = mfma(K, Q), O^T = mfma(V^T, P^T).
// C/D col = lane&31 = q for both -> all softmax state lane-local in q.
// Mask folded into QK^T C-init (additive -43000 bias, log2 domain).
// Round-10 additions: defer-max rescale (T13, THR=8), permlane32_swap for the
// P half-wave exchange (T12 primitive, replaces 8 shfl + 16 cndmask), and
// s_setprio(1) around MFMA clusters (T5; barrier-free waves = m191 regime).
// Block = 4 waves sharing 32 q rows; wave w owns KV quarter [w*512,(w+1)*512);
// 4-way merge through LDS. Grid = N*A/32 = 1024 blocks (4 blocks/CU exactly).
// __launch_bounds__(256, 4): VGPR cap 128. DO NOT raise min-waves to 8 —
// 64-VGPR cap spills acc (rounds 5/7: WRITE_SIZE 114-198 MB; keep WRITE_SIZE
// ~8 MB as the spill tripwire).
template <int PRE>
__global__ __launch_bounds__(256, 4) void attn_fwd(
    const float* __restrict__ Q, const float* __restrict__ K,
    const float* __restrict__ V, const int* __restrict__ M,
    const short* __restrict__ Kb, const short* __restrict__ Vt,
    float* __restrict__ O) {
  // bijective XCD swizzle: 1024 blocks, 128 contiguous wgs per XCD (2 batches)
  unsigned orig = blockIdx.x;
  unsigned wg = (orig & 7u) * 128u + (orig >> 3);
  int n = (int)(wg >> 6);          // 64 q-tiles per batch
  int q0 = (int)(wg & 63u) * 32;   // block's 32 q rows

  int w = threadIdx.x >> 6;  // wave 0..3 -> KV quarter
  int lane = threadIdx.x & 63;
  int hi = lane >> 5;        // half-wave id
  int li = lane & 31;

  const float* Qn = Q + (size_t)n * AQ * HD;
  const float* Kn = K + (size_t)n * BKV * HD;
  const float* Vn = V + (size_t)n * BKV * HD;
  const short* Kbn = Kb + (size_t)n * BKV * HD;
  const short* Vtn = Vt + (size_t)n * HD * BKV;
  const int* Mn = M + (size_t)n * BKV;

  __shared__ __align__(16) float pacc[4][32][68];  // 34816 B partial O^T
  __shared__ float Ml[4][2][32];                   // m, l per wave per q

  // ---- Q fragments (B operand of swapped QK^T), log2-scale folded in.
  bf16x8 qb[4];
#pragma unroll
  for (int ks = 0; ks < 4; ++ks) {
    const float* qp = Qn + (size_t)(q0 + li) * HD + 16 * ks + 8 * hi;
    f32x4 a = *(const f32x4*)qp;
    f32x4 b = *(const f32x4*)(qp + 4);
#pragma unroll
    for (int i = 0; i < 4; ++i) {
      qb[ks][i] = f2bf(a[i] * QSCALE);
      qb[ks][i + 4] = f2bf(b[i] * QSCALE);
    }
  }

  // acc0/acc1: O^T[h = 32*ht + crow(reg,hi)][q = li], crow = (r&3)+8*(r>>2)+4*hi
  f32x16 acc0 = {};
  f32x16 acc1 = {};
  float m_run = -1e30f;
  float l_run = 0.f;

  const int bstart = w * (BKV / 4);
  for (int b0 = bstart; b0 < bstart + (BKV / 4); b0 += 32) {
    // ---- mask -> C-init bias (row b_loc = 8j + 4hi + r)
    int4v mv[4];
#pragma unroll
    for (int j = 0; j < 4; ++j)
      mv[j] = *(const int4v*)(Mn + b0 + 8 * j + 4 * hi);
    f32x16 st;
#pragma unroll
    for (int j = 0; j < 4; ++j)
#pragma unroll
      for (int r = 0; r < 4; ++r) st[4 * j + r] = mv[j][r] ? MBIAS : 0.f;

    // ---- S^T = K.Q^T (+bias): st[reg] = S^T[b0 + crow(reg,hi)][q0 + li]
    __builtin_amdgcn_s_setprio(1);
#pragma unroll
    for (int ks = 0; ks < 4; ++ks) {
      bf16x8 ka;
      if constexpr (PRE) {
        ka = *(const bf16x8*)(Kbn + (size_t)(b0 + li) * HD + 16 * ks + 8 * hi);
      } else {
        const float* kp = Kn + (size_t)(b0 + li) * HD + 16 * ks + 8 * hi;
        f32x4 k0 = *(const f32x4*)kp;
        f32x4 k1 = *(const f32x4*)(kp + 4);
#pragma unroll
        for (int i = 0; i < 4; ++i) {
          ka[i] = f2bf(k0[i]);
          ka[i + 4] = f2bf(k1[i]);
        }
      }
      st = __builtin_amdgcn_mfma_f32_32x32x16_bf16(ka, qb[ks], st, 0, 0, 0);
    }
    __builtin_amdgcn_s_setprio(0);

    // ---- row max over 32 b (max3-friendly tree, then partner half via shfl)
    float a0 = fmaxf(fmaxf(st[0], st[1]), st[2]);
    float a1 = fmaxf(fmaxf(st[3], st[4]), st[5]);
    float a2 = fmaxf(fmaxf(st[6], st[7]), st[8]);
    float a3 = fmaxf(fmaxf(st[9], st[10]), st[11]);
    float a4 = fmaxf(fmaxf(st[12], st[13]), st[14]);
    float mt = fmaxf(fmaxf(fmaxf(a0, a1), fmaxf(a2, a3)), fmaxf(a4, st[15]));
    mt = fmaxf(mt, __shfl_xor(mt, 32));

    // ---- defer-max (T13): only rescale when the tile max grew past THR.
    // Invariant: acc = sum exp2(s - m_run) * V at the CURRENT m_run, so the
    // skip path is exact (P merely bounded by 2^THR instead of 1).
    if (!__all(mt - m_run <= DTHR)) {
      float m_new = fmaxf(m_run, mt);
      float fac = exp2f(m_run - m_new);
      l_run *= fac;
#pragma unroll
      for (int i = 0; i < 16; ++i) {
        acc0[i] *= fac;
        acc1[i] *= fac;
      }
      m_run = m_new;
    }

    // ---- P = exp2(S - m) in place (log2 domain; masked -> exactly 0)
    float rs = 0.f;
#pragma unroll
    for (int i = 0; i < 16; ++i) {
      float e = exp2f(st[i] - m_run);
      st[i] = e;
      rs += e;
    }
    rs += __shfl_xor(rs, 32);
    l_run += rs;

    // ---- P^T B-operand via permlane32_swap (T12): pack bf16 pairs, then each
    // swap of (w_i, w_{i+2}) yields BOTH pb words: r[0] = {lo half's word},
    // r[1] = {hi half's word} — one swap fills two output words.
    unsigned w8[8];
#pragma unroll
    for (int j = 0; j < 8; ++j) w8[j] = pk2(st[2 * j], st[2 * j + 1]);
    auto s02 = __builtin_amdgcn_permlane32_swap((int)w8[0], (int)w8[2], false, false);
    auto s13 = __builtin_amdgcn_permlane32_swap((int)w8[1], (int)w8[3], false, false);
    auto s46 = __builtin_amdgcn_permlane32_swap((int)w8[4], (int)w8[6], false, false);
    auto s57 = __builtin_amdgcn_permlane32_swap((int)w8[5], (int)w8[7], false, false);
    int4v p0 = {static_cast<int>(s02[0]), static_cast<int>(s13[0]),
                static_cast<int>(s02[1]), static_cast<int>(s13[1])};
    int4v p1 = {static_cast<int>(s46[0]), static_cast<int>(s57[0]),
                static_cast<int>(s46[1]), static_cast<int>(s57[1])};
    bf16x8 pb0 = __builtin_bit_cast(bf16x8, p0);
    bf16x8 pb1 = __builtin_bit_cast(bf16x8, p1);

    // ---- O^T += V^T . P^T : A[i=h][k=b] from Vt (contiguous bf16x8)
#pragma unroll
    for (int ht = 0; ht < 2; ++ht) {
      bf16x8 va0, va1;
      if constexpr (PRE) {
        const short* vp = Vtn + (size_t)(32 * ht + li) * BKV + b0 + 8 * hi;
        va0 = *(const bf16x8*)vp;
        va1 = *(const bf16x8*)(vp + 16);
      } else {
#pragma unroll
        for (int j = 0; j < 8; ++j) {
          va0[j] = f2bf(Vn[(size_t)(b0 + 8 * hi + j) * HD + 32 * ht + li]);
          va1[j] = f2bf(Vn[(size_t)(b0 + 16 + 8 * hi + j) * HD + 32 * ht + li]);
        }
      }
      __builtin_amdgcn_s_setprio(1);
      if (ht == 0) {
        acc0 = __builtin_amdgcn_mfma_f32_32x32x16_bf16(va0, pb0, acc0, 0, 0, 0);
        acc0 = __builtin_amdgcn_mfma_f32_32x32x16_bf16(va1, pb1, acc0, 0, 0, 0);
      } else {
        acc1 = __builtin_amdgcn_mfma_f32_32x32x16_bf16(va0, pb0, acc1, 0, 0, 0);
        acc1 = __builtin_amdgcn_mfma_f32_32x32x16_bf16(va1, pb1, acc1, 0, 0, 0);
      }
      __builtin_amdgcn_s_setprio(0);
    }
  }

  // ---- publish per-wave partials (m, l lane-local; acc^T scattered to [q][h])
  if (hi == 0) {
    Ml[w][0][li] = m_run;
    Ml[w][1][li] = l_run;
  }
#pragma unroll
  for (int reg = 0; reg < 16; ++reg) {
    int hrow = (reg & 3) + 8 * (reg >> 2) + 4 * hi;
    pacc[w][li][hrow] = acc0[reg];
    pacc[w][li][32 + hrow] = acc1[reg];
  }
  __syncthreads();

  // ---- merge 4 KV-quarter partials; 256 threads cover 32 q x 8 h-octets
  {
    int tid = threadIdx.x;
    int q = tid >> 3;          // 0..31
    int hb = (tid & 7) * 8;    // 0,8,...,56
    float m0 = Ml[0][0][q], m1 = Ml[1][0][q];
    float m2 = Ml[2][0][q], m3 = Ml[3][0][q];
    float mmax = fmaxf(fmaxf(m0, m1), fmaxf(m2, m3));
    float f[4] = {exp2f(m0 - mmax), exp2f(m1 - mmax), exp2f(m2 - mmax),
                  exp2f(m3 - mmax)};
    float l = f[0] * Ml[0][1][q] + f[1] * Ml[1][1][q] + f[2] * Ml[2][1][q] +
              f[3] * Ml[3][1][q];
    float inv = 1.0f / l;
    float* op = O + ((size_t)n * AQ + q0 + q) * HD + hb;
#pragma unroll
    for (int t = 0; t < 2; ++t) {
      f32x4 o = {0.f, 0.f, 0.f, 0.f};
#pragma unroll
      for (int ww = 0; ww < 4; ++ww) {
        f32x4 a = *(const f32x4*)&pacc[ww][q][hb + 4 * t];
#pragma unroll
        for (int i = 0; i < 4; ++i) o[i] += f[ww] * a[i];
      }
      f32x4 res;
#pragma unroll
      for (int i = 0; i < 4; ++i) res[i] = o[i] * inv;
      *(f32x4*)(op + 4 * t) = res;
    }
  }
}

extern "C" void kernel_launch(void* const* d_in, const int* in_sizes, int n_in,
                              void* d_out, int out_size, void* d_ws, size_t ws_size,
                              hipStream_t stream) {
  const float* q = (const float*)d_in[0];
  const float* k = (const float*)d_in[1];
  const float* v = (const float*)d_in[2];
  const int* m = (const int*)d_in[3];
  float* o = (float*)d_out;

  const size_t kv_elems = (size_t)NB * BKV * HD;     // 2,097,152
  const size_t need = kv_elems * 2 * sizeof(short);  // Kb + Vt = 8 MB

  if (ws_size >= need) {
    short* kb = (short*)d_ws;
    short* vt = kb + kv_elems;
    prepack<<<dim3(1536), dim3(256), 0, stream>>>(k, v, kb, vt);
    attn_fwd<1><<<dim3(NB * (AQ / 32)), dim3(256), 0, stream>>>(q, k, v, m, kb, vt, o);
  } else {
    attn_fwd<0><<<dim3(NB * (AQ / 32)), dim3(256), 0, stream>>>(q, k, v, m, nullptr, nullptr, o);
  }
}

// Round 13
// 140.860 us; speedup vs baseline: 1.0553x; 1.0476x over previous
//
#include <hip/hip_runtime.h>

// Problem constants (reference: N=16, A=2048, B=2048, H=64)
#define NB 16
#define AQ 2048
#define BKV 2048
#define HD 64

#define QSCALE 0.18033688f  // 0.125 * log2(e): softmax done in log2 domain
#define MBIAS -43000.0f     // additive mask bias (log2 units); exp2 -> exact 0
#define DTHR 8.0f           // defer-max threshold (log2 units): P <= 2^8

typedef float f32x4 __attribute__((ext_vector_type(4)));
typedef float f32x16 __attribute__((ext_vector_type(16)));
typedef short bf16x8 __attribute__((ext_vector_type(8)));
typedef int int4v __attribute__((ext_vector_type(4)));

__device__ __forceinline__ short f2bf(float f) {
  return __builtin_bit_cast(short, static_cast<__bf16>(f));
}
__device__ __forceinline__ unsigned pk2(float a, float b) {
  unsigned lo = (unsigned short)f2bf(a);
  unsigned hh = (unsigned short)f2bf(b);
  return lo | (hh << 16);
}

// -------------------- fused prepass (single launch) --------------------------
// blocks [0, 1024):    K f32 [n][b][h] -> Kb bf16 [n][b][h]
// blocks [1024, 1536): V f32 [n][b][h] -> Vt bf16 [n][h][b]  (64x64 LDS tile)
// blocks [1536, 1540): mask int32 [n][b] -> Mb bitmask [n][64] (bit b = masked)
__global__ __launch_bounds__(256) void prepack(const float* __restrict__ K,
                                               const float* __restrict__ V,
                                               const int* __restrict__ M,
                                               short* __restrict__ Kb,
                                               short* __restrict__ Vt,
                                               unsigned* __restrict__ Mb) {
  if (blockIdx.x < 1024) {
    size_t base = ((size_t)blockIdx.x * 256 + threadIdx.x) * 8;
    f32x4 a = *(const f32x4*)(K + base);
    f32x4 b = *(const f32x4*)(K + base + 4);
    bf16x8 o;
#pragma unroll
    for (int i = 0; i < 4; ++i) {
      o[i] = f2bf(a[i]);
      o[i + 4] = f2bf(b[i]);
    }
    *(bf16x8*)(Kb + base) = o;
  } else if (blockIdx.x < 1536) {
    unsigned vb = blockIdx.x - 1024;
    int n = vb >> 5;
    int b0 = (vb & 31) * 64;
    int t = threadIdx.x;
    __shared__ short tile[64][68];
    int rb = t >> 4;
    int hc = (t & 15) * 4;
#pragma unroll
    for (int j = 0; j < 4; ++j) {
      int r = rb + 16 * j;
      f32x4 v = *(const f32x4*)(V + ((size_t)n * BKV + b0 + r) * HD + hc);
#pragma unroll
      for (int i = 0; i < 4; ++i) tile[r][hc + i] = f2bf(v[i]);
    }
    __syncthreads();
    int hr = t >> 2;
    int bb = (t & 3) * 16;
    bf16x8 o0, o1;
#pragma unroll
    for (int j = 0; j < 8; ++j) {
      o0[j] = tile[bb + j][hr];
      o1[j] = tile[bb + 8 + j][hr];
    }
    short* dst = Vt + ((size_t)n * HD + hr) * BKV + b0 + bb;
    *(bf16x8*)dst = o0;
    *(bf16x8*)(dst + 8) = o1;
  } else {
    unsigned gw = (blockIdx.x - 1536) * 256 + threadIdx.x;  // 0..1023
    int n = (int)(gw >> 6);
    int ww = (int)(gw & 63u);
    const int* src = M + (size_t)n * BKV + ww * 32;
    unsigned bits = 0;
#pragma unroll
    for (int j = 0; j < 32; ++j) bits |= (src[j] ? 1u : 0u) << j;
    Mb[n * 64 + ww] = bits;
  }
}

// ---------------------------- main flash kernel ------------------------------
// 32x32x16 MFMA, BOTH GEMMs swapped: S^T = mfma(K, Q), O^T = mfma(V^T, P^T).
// C/D col = lane&31 = q for both -> all softmax state lane-local in q.
// Mask folded into QK^T C-init from a PREPACKED BITMASK (1 scalar word/tile).
// Round-13: software-pipelined tile loop (round-12 post-mortem: ~2900 cyc/tile
// with all pipes <40% busy = serial L2 latency per tile). K fragments are
// double-buffered one tile ahead; mask word prefetched ahead; V loads issue at
// tile start, consumed after softmax. Ping-pong via 2x-unrolled loop body
// (static indexing — runtime-indexed buffers would spill to scratch).
// Block = 4 waves sharing 32 q rows; wave w owns KV quarter [w*512,(w+1)*512);
// 4-way merge through LDS. Grid = N*A/32 = 1024 blocks.
// __launch_bounds__(256, 3): VGPR cap ~170, kernel needs ~130-150 — NO spill.
// Spill tripwire: WRITE_SIZE must stay ~8 MB (rounds 5/7: 114-198 MB = spill).
template <int PRE>
__global__ __launch_bounds__(256, 3) void attn_fwd(
    const float* __restrict__ Q, const float* __restrict__ K,
    const float* __restrict__ V, const int* __restrict__ M,
    const short* __restrict__ Kb, const short* __restrict__ Vt,
    const unsigned* __restrict__ Mb, float* __restrict__ O) {
  // bijective XCD swizzle: 1024 blocks, 128 contiguous wgs per XCD (2 batches)
  unsigned orig = blockIdx.x;
  unsigned wg = (orig & 7u) * 128u + (orig >> 3);
  int n = (int)(wg >> 6);          // 64 q-tiles per batch
  int q0 = (int)(wg & 63u) * 32;   // block's 32 q rows

  int w = threadIdx.x >> 6;  // wave 0..3 -> KV quarter
  int lane = threadIdx.x & 63;
  int hi = lane >> 5;        // half-wave id
  int li = lane & 31;

  const float* Qn = Q + (size_t)n * AQ * HD;
  const float* Kn = K + (size_t)n * BKV * HD;
  const float* Vn = V + (size_t)n * BKV * HD;
  const short* Kbn = Kb + (size_t)n * BKV * HD;
  const short* Vtn = Vt + (size_t)n * HD * BKV;
  const unsigned* Mbn = Mb + (size_t)n * 64;
  const int* Mn = M + (size_t)n * BKV;

  __shared__ __align__(16) float pacc[4][32][68];  // 34816 B partial O^T
  __shared__ float Ml[4][2][32];                   // m, l per wave per q

  // ---- Q fragments (B operand of swapped QK^T), log2-scale folded in.
  bf16x8 qb[4];
#pragma unroll
  for (int ks = 0; ks < 4; ++ks) {
    const float* qp = Qn + (size_t)(q0 + li) * HD + 16 * ks + 8 * hi;
    f32x4 a = *(const f32x4*)qp;
    f32x4 b = *(const f32x4*)(qp + 4);
#pragma unroll
    for (int i = 0; i < 4; ++i) {
      qb[ks][i] = f2bf(a[i] * QSCALE);
      qb[ks][i + 4] = f2bf(b[i] * QSCALE);
    }
  }

  // acc0/acc1: O^T[h = 32*ht + crow(reg,hi)][q = li], crow = (r&3)+8*(r>>2)+4*hi
  f32x16 acc0 = {};
  f32x16 acc1 = {};
  float m_run = -1e30f;
  float l_run = 0.f;

  const int bstart = w * (BKV / 4);

  // ---- K-fragment loader (one tile = 4 bf16x8)
  auto LOADK = [&](int b0, bf16x8(&ka)[4]) {
#pragma unroll
    for (int ks = 0; ks < 4; ++ks) {
      if constexpr (PRE) {
        ka[ks] = *(const bf16x8*)(Kbn + (size_t)(b0 + li) * HD + 16 * ks + 8 * hi);
      } else {
        const float* kp = Kn + (size_t)(b0 + li) * HD + 16 * ks + 8 * hi;
        f32x4 k0 = *(const f32x4*)kp;
        f32x4 k1 = *(const f32x4*)(kp + 4);
#pragma unroll
        for (int i = 0; i < 4; ++i) {
          ka[ks][i] = f2bf(k0[i]);
          ka[ks][i + 4] = f2bf(k1[i]);
        }
      }
    }
  };
  auto LOADMB = [&](int b0) -> unsigned {
    if constexpr (PRE) return Mbn[b0 >> 5];
    return 0u;
  };

  // ---- one full KV tile (32 b): V loads issue FIRST (consumed after softmax)
  auto TILE = [&](int b0, const bf16x8(&ka)[4], unsigned mb) {
    bf16x8 va0, va1, va2, va3;
    if constexpr (PRE) {
      const short* vp0 = Vtn + (size_t)li * BKV + b0 + 8 * hi;
      const short* vp1 = Vtn + (size_t)(32 + li) * BKV + b0 + 8 * hi;
      va0 = *(const bf16x8*)vp0;
      va1 = *(const bf16x8*)(vp0 + 16);
      va2 = *(const bf16x8*)vp1;
      va3 = *(const bf16x8*)(vp1 + 16);
    } else {
#pragma unroll
      for (int j = 0; j < 8; ++j) {
        va0[j] = f2bf(Vn[(size_t)(b0 + 8 * hi + j) * HD + li]);
        va1[j] = f2bf(Vn[(size_t)(b0 + 16 + 8 * hi + j) * HD + li]);
        va2[j] = f2bf(Vn[(size_t)(b0 + 8 * hi + j) * HD + 32 + li]);
        va3[j] = f2bf(Vn[(size_t)(b0 + 16 + 8 * hi + j) * HD + 32 + li]);
      }
    }

    // ---- mask bits -> C-init bias (row b_loc = crow(reg,hi) = pos + 4*hi)
    f32x16 st;
    if constexpr (PRE) {
      unsigned ub = mb >> (4 * hi);
#pragma unroll
      for (int r = 0; r < 16; ++r) {
        int pos = (r & 3) + 8 * (r >> 2);
        st[r] = ((ub >> pos) & 1u) ? MBIAS : 0.f;
      }
    } else {
      int4v mv[4];
#pragma unroll
      for (int j = 0; j < 4; ++j) mv[j] = *(const int4v*)(Mn + b0 + 8 * j + 4 * hi);
#pragma unroll
      for (int j = 0; j < 4; ++j)
#pragma unroll
        for (int r = 0; r < 4; ++r) st[4 * j + r] = mv[j][r] ? MBIAS : 0.f;
    }

    // ---- S^T = K.Q^T (+bias)
#pragma unroll
    for (int ks = 0; ks < 4; ++ks)
      st = __builtin_amdgcn_mfma_f32_32x32x16_bf16(ka[ks], qb[ks], st, 0, 0, 0);

    // ---- row max (tree), partner half via one shfl
    float a0 = fmaxf(fmaxf(st[0], st[1]), st[2]);
    float a1 = fmaxf(fmaxf(st[3], st[4]), st[5]);
    float a2 = fmaxf(fmaxf(st[6], st[7]), st[8]);
    float a3 = fmaxf(fmaxf(st[9], st[10]), st[11]);
    float a4 = fmaxf(fmaxf(st[12], st[13]), st[14]);
    float mt = fmaxf(fmaxf(fmaxf(a0, a1), fmaxf(a2, a3)), fmaxf(a4, st[15]));
    mt = fmaxf(mt, __shfl_xor(mt, 32));

    // ---- defer-max (T13): skip rescale unless tile max grew past THR
    if (!__all(mt - m_run <= DTHR)) {
      float m_new = fmaxf(m_run, mt);
      float fac = exp2f(m_run - m_new);
      l_run *= fac;
#pragma unroll
      for (int i = 0; i < 16; ++i) {
        acc0[i] *= fac;
        acc1[i] *= fac;
      }
      m_run = m_new;
    }

    // ---- P = exp2(S - m) in place; pairwise sum tree
#pragma unroll
    for (int i = 0; i < 16; ++i) st[i] = exp2f(st[i] - m_run);
    float s0 = (st[0] + st[1]) + (st[2] + st[3]);
    float s1 = (st[4] + st[5]) + (st[6] + st[7]);
    float s2 = (st[8] + st[9]) + (st[10] + st[11]);
    float s3 = (st[12] + st[13]) + (st[14] + st[15]);
    float rs = (s0 + s1) + (s2 + s3);
    rs += __shfl_xor(rs, 32);
    l_run += rs;

    // ---- P^T B-operand via permlane32_swap (one swap fills two words)
    unsigned w8[8];
#pragma unroll
    for (int j = 0; j < 8; ++j) w8[j] = pk2(st[2 * j], st[2 * j + 1]);
    auto s02 = __builtin_amdgcn_permlane32_swap((int)w8[0], (int)w8[2], false, false);
    auto s13 = __builtin_amdgcn_permlane32_swap((int)w8[1], (int)w8[3], false, false);
    auto s46 = __builtin_amdgcn_permlane32_swap((int)w8[4], (int)w8[6], false, false);
    auto s57 = __builtin_amdgcn_permlane32_swap((int)w8[5], (int)w8[7], false, false);
    int4v p0 = {static_cast<int>(s02[0]), static_cast<int>(s13[0]),
                static_cast<int>(s02[1]), static_cast<int>(s13[1])};
    int4v p1 = {static_cast<int>(s46[0]), static_cast<int>(s57[0]),
                static_cast<int>(s46[1]), static_cast<int>(s57[1])};
    bf16x8 pb0 = __builtin_bit_cast(bf16x8, p0);
    bf16x8 pb1 = __builtin_bit_cast(bf16x8, p1);

    // ---- O^T += V^T . P^T
    acc0 = __builtin_amdgcn_mfma_f32_32x32x16_bf16(va0, pb0, acc0, 0, 0, 0);
    acc0 = __builtin_amdgcn_mfma_f32_32x32x16_bf16(va1, pb1, acc0, 0, 0, 0);
    acc1 = __builtin_amdgcn_mfma_f32_32x32x16_bf16(va2, pb0, acc1, 0, 0, 0);
    acc1 = __builtin_amdgcn_mfma_f32_32x32x16_bf16(va3, pb1, acc1, 0, 0, 0);
  };

  // ---- software-pipelined loop: K/mask for tile t+1 always in flight
  bf16x8 kaA[4], kaB[4];
  LOADK(bstart, kaA);
  unsigned mbA = LOADMB(bstart), mbB;
#pragma unroll 1
  for (int t = 0; t < 16; t += 2) {
    const int b0 = bstart + t * 32;
    LOADK(b0 + 32, kaB);          // prefetch tile t+1 (cover = full TILE)
    mbB = LOADMB(b0 + 32);
    TILE(b0, kaA, mbA);
    if (t < 14) {
      LOADK(b0 + 64, kaA);        // prefetch tile t+2
      mbA = LOADMB(b0 + 64);
    }
    TILE(b0 + 32, kaB, mbB);
  }

  // ---- publish per-wave partials (m, l lane-local; acc^T scattered to [q][h])
  if (hi == 0) {
    Ml[w][0][li] = m_run;
    Ml[w][1][li] = l_run;
  }
#pragma unroll
  for (int reg = 0; reg < 16; ++reg) {
    int hrow = (reg & 3) + 8 * (reg >> 2) + 4 * hi;
    pacc[w][li][hrow] = acc0[reg];
    pacc[w][li][32 + hrow] = acc1[reg];
  }
  __syncthreads();

  // ---- merge 4 KV-quarter partials; 256 threads cover 32 q x 8 h-octets
  {
    int tid = threadIdx.x;
    int q = tid >> 3;          // 0..31
    int hb = (tid & 7) * 8;    // 0,8,...,56
    float m0 = Ml[0][0][q], m1 = Ml[1][0][q];
    float m2 = Ml[2][0][q], m3 = Ml[3][0][q];
    float mmax = fmaxf(fmaxf(m0, m1), fmaxf(m2, m3));
    float f[4] = {exp2f(m0 - mmax), exp2f(m1 - mmax), exp2f(m2 - mmax),
                  exp2f(m3 - mmax)};
    float l = f[0] * Ml[0][1][q] + f[1] * Ml[1][1][q] + f[2] * Ml[2][1][q] +
              f[3] * Ml[3][1][q];
    float inv = 1.0f / l;
    float* op = O + ((size_t)n * AQ + q0 + q) * HD + hb;
#pragma unroll
    for (int t = 0; t < 2; ++t) {
      f32x4 o = {0.f, 0.f, 0.f, 0.f};
#pragma unroll
      for (int ww = 0; ww < 4; ++ww) {
        f32x4 a = *(const f32x4*)&pacc[ww][q][hb + 4 * t];
#pragma unroll
        for (int i = 0; i < 4; ++i) o[i] += f[ww] * a[i];
      }
      f32x4 res;
#pragma unroll
      for (int i = 0; i < 4; ++i) res[i] = o[i] * inv;
      *(f32x4*)(op + 4 * t) = res;
    }
  }
}

extern "C" void kernel_launch(void* const* d_in, const int* in_sizes, int n_in,
                              void* d_out, int out_size, void* d_ws, size_t ws_size,
                              hipStream_t stream) {
  const float* q = (const float*)d_in[0];
  const float* k = (const float*)d_in[1];
  const float* v = (const float*)d_in[2];
  const int* m = (const int*)d_in[3];
  float* o = (float*)d_out;

  const size_t kv_elems = (size_t)NB * BKV * HD;  // 2,097,152
  const size_t mb_words = (size_t)NB * 64;        // 1024
  const size_t need = kv_elems * 2 * sizeof(short) + mb_words * 4;  // ~8 MB

  if (ws_size >= need) {
    short* kb = (short*)d_ws;
    short* vt = kb + kv_elems;
    unsigned* mb = (unsigned*)(vt + kv_elems);
    prepack<<<dim3(1540), dim3(256), 0, stream>>>(k, v, m, kb, vt, mb);
    attn_fwd<1><<<dim3(NB * (AQ / 32)), dim3(256), 0, stream>>>(q, k, v, m, kb, vt, mb, o);
  } else {
    attn_fwd<0><<<dim3(NB * (AQ / 32)), dim3(256), 0, stream>>>(q, k, v, m, nullptr, nullptr, nullptr, o);
  }
}